// Round 1
// baseline (600.163 us; speedup 1.0000x reference)
//
#include <hip/hip_runtime.h>
#include <math.h>

// FineMatching: one block per m (M=8192), 256 threads.
// Layout of d_out (fp32, concat): mkpts0_f[M][2] | mkpts1_f[M][2] | probs[M][9] | sm[M][64][64]

constexpr int TPB = 256;

__global__ __launch_bounds__(TPB, 2) void fine_matching_kernel(
    const float* __restrict__ feat0,   // [M][64][64]
    const float* __restrict__ feat1,   // [M][100][64]
    const float* __restrict__ mk0,     // [M][2]
    const float* __restrict__ mk1,     // [M][2]
    const int* __restrict__ hw0_i,
    const int* __restrict__ hw0_f,
    float* __restrict__ out, int M)
{
    constexpr int F0S = 68;   // stride pad: 68*4B = 272B -> 2-way max bank aliasing (free)
    constexpr int F1S = 68;
    constexpr int CS  = 101;  // odd stride: row & col scans both ~2-way

    __shared__ float s_f0[64 * F0S];      // reused as sm[64][64] in phase D
    __shared__ float s_f1[112 * F1S];     // rows 100..111 zero-padded
    __shared__ float s_conf[64 * CS];
    __shared__ float s_ff0[64 * 8];       // last-8 channels of feat0 (survives f0 overwrite)
    __shared__ float s_cmax[100], s_csum[100], s_rmax[64], s_rsum[64];
    __shared__ float s_rval[TPB];
    __shared__ int   s_ridx[TPB];
    __shared__ float s_win[9];

    const int m = blockIdx.x;
    const int t = threadIdx.x;
    const float scale = (float)hw0_i[0] / (float)hw0_f[0];   // 832/416 = 2.0

    const float* g0 = feat0 + (size_t)m * 4096;
    const float* g1 = feat1 + (size_t)m * 6400;

    // ---- Phase A: stage feat0 / feat1 into LDS (float4 coalesced) ----
    for (int i = t; i < 1024; i += TPB) {          // 64*64/4
        float4 v = ((const float4*)g0)[i];
        int fl = i << 2; int l = fl >> 6; int c = fl & 63;
        *(float4*)&s_f0[l * F0S + c] = v;
    }
    for (int i = t; i < 1600; i += TPB) {          // 100*64/4
        float4 v = ((const float4*)g1)[i];
        int fl = i << 2; int l = fl >> 6; int c = fl & 63;
        *(float4*)&s_f1[l * F1S + c] = v;
    }
    for (int i = t; i < 12 * F1S; i += TPB)        // zero pad rows 100..111
        s_f1[100 * F1S + i] = 0.0f;
    __syncthreads();

    // keep ff channels of feat0 alive past the s_f0 -> sm overwrite
    for (int i = t; i < 512; i += TPB) {
        int l = i >> 3, c = i & 7;
        s_ff0[i] = s_f0[l * F0S + 56 + c];
    }

    // ---- Phase B: conf_f = f0[:, :56] @ f1[:, :56]^T / 64  (4x7 register tile) ----
    const int tr = t & 15;          // -> r = tr + 16*jj
    const int l0 = (t >> 4) * 4;    // -> l = l0 + j
    float acc[4][7];
    #pragma unroll
    for (int j = 0; j < 4; j++)
        #pragma unroll
        for (int jj = 0; jj < 7; jj++) acc[j][jj] = 0.0f;

    for (int k = 0; k < 56; k += 4) {
        float4 a[4], b[7];
        #pragma unroll
        for (int j = 0; j < 4; j++) a[j] = *(const float4*)&s_f0[(l0 + j) * F0S + k];
        #pragma unroll
        for (int jj = 0; jj < 7; jj++) b[jj] = *(const float4*)&s_f1[(tr + 16 * jj) * F1S + k];
        #pragma unroll
        for (int j = 0; j < 4; j++)
            #pragma unroll
            for (int jj = 0; jj < 7; jj++)
                acc[j][jj] += a[j].x * b[jj].x + a[j].y * b[jj].y
                            + a[j].z * b[jj].z + a[j].w * b[jj].w;
    }
    #pragma unroll
    for (int j = 0; j < 4; j++)
        #pragma unroll
        for (int jj = 0; jj < 7; jj++) {
            int r = tr + 16 * jj;
            float v = acc[j][jj] * (1.0f / 64.0f);
            acc[j][jj] = v;                         // keep in regs for phase D
            if (r < 100) s_conf[(l0 + j) * CS + r] = v;
        }
    __syncthreads();

    // ---- Phase C: softmax stats along both axes (parallel thread groups) ----
    if (t < 100) {                                   // per-column r: over l (axis=1)
        int r = t;
        float mx = -INFINITY;
        for (int l = 0; l < 64; l++) mx = fmaxf(mx, s_conf[l * CS + r]);
        float sum = 0.0f;
        for (int l = 0; l < 64; l++) sum += __expf(s_conf[l * CS + r] - mx);
        s_cmax[r] = mx; s_csum[r] = sum;
    } else if (t < 164) {                            // per-row l: over r (axis=2)
        int l = t - 100;
        float mx = -INFINITY;
        for (int r = 0; r < 100; r++) mx = fmaxf(mx, s_conf[l * CS + r]);
        float sum = 0.0f;
        for (int r = 0; r < 100; r++) sum += __expf(s_conf[l * CS + r] - mx);
        s_rmax[l] = mx; s_rsum[l] = sum;
    }
    __syncthreads();

    // ---- Phase D: sm = exp(2x - cm - rm)/(cs*rs), crop 10x10 -> 8x8, local argmax ----
    float* s_sm = s_f0;                              // overwrite retired f0 region
    float bestv = -INFINITY; int besti = 0x7fffffff;
    #pragma unroll
    for (int j = 0; j < 4; j++) {
        int l = l0 + j;
        float rm = s_rmax[l], rs = s_rsum[l];
        #pragma unroll
        for (int jj = 0; jj < 7; jj++) {
            int r = tr + 16 * jj;
            if (r < 100) {
                int ri = r / 10, rj = r % 10;
                if (ri >= 1 && ri <= 8 && rj >= 1 && rj <= 8) {
                    float v = __expf(2.0f * acc[j][jj] - s_cmax[r] - rm)
                              / (s_csum[r] * rs);
                    int flat = l * 64 + (ri - 1) * 8 + (rj - 1);
                    s_sm[flat] = v;
                    if (v > bestv) { bestv = v; besti = flat; }  // ascending flat order
                }
            }
        }
    }
    s_rval[t] = bestv; s_ridx[t] = besti;
    __syncthreads();
    for (int s = 128; s > 0; s >>= 1) {              // argmax reduce, first-index ties
        if (t < s) {
            float v2 = s_rval[t + s]; int i2 = s_ridx[t + s];
            if (v2 > s_rval[t] || (v2 == s_rval[t] && i2 < s_ridx[t])) {
                s_rval[t] = v2; s_ridx[t] = i2;
            }
        }
        __syncthreads();
    }
    const int best  = s_ridx[0];
    const int idx_l = best >> 6;
    const int idx_r = best & 63;
    const int iids  = idx_r >> 3, jids = idx_r & 7;

    // ---- sm -> global (float4) ----
    float* o_sm = out + (size_t)13 * M + (size_t)m * 4096;
    for (int i = t; i < 1024; i += TPB)
        ((float4*)o_sm)[i] = ((const float4*)s_sm)[i];

    // ---- Phase E: 3x3 conf_ff window (recomputed: 9 dots of length 8) ----
    if (t < 9) {
        int da = t / 3 - 1, db = t % 3 - 1;
        int wi = iids + da; if (wi < 0) wi += 10;
        int wj = jids + db; if (wj < 0) wj += 10;
        int rp = wi * 10 + wj;
        float dot = 0.0f;
        #pragma unroll
        for (int c = 0; c < 8; c++)
            dot += s_ff0[idx_l * 8 + c] * s_f1[rp * F1S + 56 + c];
        s_win[t] = dot * 0.35355339059327373f;       // 1/sqrt(8)
    }
    __syncthreads();

    if (t == 0) {
        float w[9], mx = -INFINITY;
        #pragma unroll
        for (int i = 0; i < 9; i++) { w[i] = s_win[i] * 0.1f; mx = fmaxf(mx, w[i]); }
        float sum = 0.0f;
        #pragma unroll
        for (int i = 0; i < 9; i++) { w[i] = __expf(w[i] - mx); sum += w[i]; }
        float inv = 1.0f / sum;
        float* o_probs = out + (size_t)4 * M + (size_t)m * 9;
        float cx = 0.0f, cy = 0.0f;
        #pragma unroll
        for (int i = 0; i < 9; i++) {
            float p = w[i] * inv;
            o_probs[i] = p;
            cx += p * (float)(i % 3 - 1);            // pos along columns
            cy += p * (float)(i / 3 - 1);            // pos along rows
        }
        float dlx = (float)(idx_l & 7) - 3.5f;
        float dly = (float)(idx_l >> 3) - 3.5f;
        out[2 * m]     = mk0[2 * m]     + dlx * scale;
        out[2 * m + 1] = mk0[2 * m + 1] + dly * scale;
        float drx = (float)jids - 3.5f;
        float dry = (float)iids - 3.5f;
        float* o1 = out + (size_t)2 * M;
        o1[2 * m]     = mk1[2 * m]     + (drx + cx) * scale;
        o1[2 * m + 1] = mk1[2 * m + 1] + (dry + cy) * scale;
    }
}

extern "C" void kernel_launch(void* const* d_in, const int* in_sizes, int n_in,
                              void* d_out, int out_size, void* d_ws, size_t ws_size,
                              hipStream_t stream) {
    const float* feat0 = (const float*)d_in[0];
    const float* feat1 = (const float*)d_in[1];
    const float* mk0   = (const float*)d_in[2];
    const float* mk1   = (const float*)d_in[3];
    const int*   hw0_i = (const int*)d_in[6];
    const int*   hw0_f = (const int*)d_in[7];
    const int M = in_sizes[0] / 4096;   // feat0 = M*64*64

    fine_matching_kernel<<<M, TPB, 0, stream>>>(
        feat0, feat1, mk0, mk1, hw0_i, hw0_f, (float*)d_out, M);
}

// Round 2
// 485.189 us; speedup vs baseline: 1.2370x; 1.2370x over previous
//
#include <hip/hip_runtime.h>
#include <math.h>
#include <limits.h>

// FineMatching: one block per m (M=8192), 256 threads, 3 blocks/CU.
// d_out (fp32 concat): mkpts0_f[M][2] | mkpts1_f[M][2] | probs[M][9] | sm[M][64][64]

constexpr int TPB = 256;

__global__ __launch_bounds__(TPB, 3) void fine_matching_kernel(
    const float* __restrict__ feat0,   // [M][64][64]
    const float* __restrict__ feat1,   // [M][100][64]
    const float* __restrict__ mk0,     // [M][2]
    const float* __restrict__ mk1,     // [M][2]
    const int* __restrict__ hw0_i,
    const int* __restrict__ hw0_f,
    float* __restrict__ out, int M)
{
    constexpr int F0S = 68;   // pad: 2-way max bank aliasing (free per m136)
    constexpr int F1S = 68;

    __shared__ float s_f0[64 * F0S];      // reused as sm[64][64] staging later
    __shared__ float s_f1[100 * F1S];
    __shared__ float s_ff0[64 * 8];       // last-8 channels of feat0
    __shared__ float s_rsum[64];
    __shared__ float s_cpart[4][112];     // per-wave col partials
    __shared__ float s_csum[112];
    __shared__ float s_wval[4];
    __shared__ int   s_widx[4];
    __shared__ float s_win[9];

    const int m = blockIdx.x;
    const int t = threadIdx.x;
    const int w = t >> 6;
    const float scale = (float)hw0_i[0] / (float)hw0_f[0];   // 2.0

    const float* g0 = feat0 + (size_t)m * 4096;
    const float* g1 = feat1 + (size_t)m * 6400;

    // ---- stage feat0/feat1 into LDS (float4 coalesced) ----
    for (int i = t; i < 1024; i += TPB) {
        float4 v = ((const float4*)g0)[i];
        int fl = i << 2; int l = fl >> 6; int c = fl & 63;
        *(float4*)&s_f0[l * F0S + c] = v;
    }
    for (int i = t; i < 1600; i += TPB) {
        float4 v = ((const float4*)g1)[i];
        int fl = i << 2; int l = fl >> 6; int c = fl & 63;
        *(float4*)&s_f1[l * F1S + c] = v;
    }
    __syncthreads();

    // keep ff channels of feat0 alive past the s_f0 -> sm overwrite
    for (int i = t; i < 512; i += TPB) {
        int l = i >> 3, c = i & 7;
        s_ff0[i] = s_f0[l * F0S + 56 + c];
    }

    // ---- GEMM: conf = f0[:, :56] @ f1[:, :56]^T / 64, 4x7 register tile ----
    const int tr = t & 15;          // r = tr + 16*jj
    const int l0 = (t >> 4) * 4;    // l = l0 + j
    int  boff[7];
    bool rmask[7];
    #pragma unroll
    for (int jj = 0; jj < 7; jj++) {
        int r = tr + 16 * jj;
        rmask[jj] = (r < 100);
        boff[jj] = (rmask[jj] ? r : 99) * F1S;   // clamp: valid addr, masked result
    }

    float acc[4][7];
    #pragma unroll
    for (int j = 0; j < 4; j++)
        #pragma unroll
        for (int jj = 0; jj < 7; jj++) acc[j][jj] = 0.0f;

    for (int k = 0; k < 56; k += 4) {
        float4 a[4], b[7];
        #pragma unroll
        for (int j = 0; j < 4; j++) a[j] = *(const float4*)&s_f0[(l0 + j) * F0S + k];
        #pragma unroll
        for (int jj = 0; jj < 7; jj++) b[jj] = *(const float4*)&s_f1[boff[jj] + k];
        #pragma unroll
        for (int j = 0; j < 4; j++)
            #pragma unroll
            for (int jj = 0; jj < 7; jj++)
                acc[j][jj] += a[j].x * b[jj].x + a[j].y * b[jj].y
                            + a[j].z * b[jj].z + a[j].w * b[jj].w;
    }

    // p = exp(conf) (no max-subtract: conf is O(1), softmax is shift-invariant)
    #pragma unroll
    for (int j = 0; j < 4; j++)
        #pragma unroll
        for (int jj = 0; jj < 7; jj++) {
            float c = acc[j][jj] * (1.0f / 64.0f);
            acc[j][jj] = rmask[jj] ? __expf(c) : 0.0f;
        }

    // row sums (over r, per l): reduce across the 16 lanes sharing l0
    float prow[4];
    #pragma unroll
    for (int j = 0; j < 4; j++) {
        float s = 0.0f;
        #pragma unroll
        for (int jj = 0; jj < 7; jj++) s += acc[j][jj];
        prow[j] = s;
    }
    #pragma unroll
    for (int d = 1; d < 16; d <<= 1)
        #pragma unroll
        for (int j = 0; j < 4; j++) prow[j] += __shfl_xor(prow[j], d);
    if (tr == 0) {
        #pragma unroll
        for (int j = 0; j < 4; j++) s_rsum[l0 + j] = prow[j];
    }

    // col sums (over l, per r): reduce 4 in-thread + xor16/32 in-wave + 4 waves via LDS
    float pcol[7];
    #pragma unroll
    for (int jj = 0; jj < 7; jj++)
        pcol[jj] = acc[0][jj] + acc[1][jj] + acc[2][jj] + acc[3][jj];
    #pragma unroll
    for (int jj = 0; jj < 7; jj++) {
        pcol[jj] += __shfl_xor(pcol[jj], 16);
        pcol[jj] += __shfl_xor(pcol[jj], 32);
    }
    if ((t & 63) < 16) {
        #pragma unroll
        for (int jj = 0; jj < 7; jj++) s_cpart[w][tr + 16 * jj] = pcol[jj];
    }
    __syncthreads();
    if (t < 112)
        s_csum[t] = s_cpart[0][t] + s_cpart[1][t] + s_cpart[2][t] + s_cpart[3][t];
    __syncthreads();

    // ---- sm = p^2/(rsum*csum), crop 10x10 -> 8x8, argmax ----
    float invr[4], invc[7];
    #pragma unroll
    for (int j = 0; j < 4; j++) invr[j] = 1.0f / s_rsum[l0 + j];
    #pragma unroll
    for (int jj = 0; jj < 7; jj++)
        invc[jj] = rmask[jj] ? (1.0f / s_csum[tr + 16 * jj]) : 0.0f;

    float* s_sm = s_f0;                  // overwrite retired f0 region
    float bestv = -INFINITY; int besti = INT_MAX;
    #pragma unroll
    for (int j = 0; j < 4; j++) {
        int l = l0 + j;
        #pragma unroll
        for (int jj = 0; jj < 7; jj++) {
            if (rmask[jj]) {
                int r = tr + 16 * jj;
                int ri = r / 10, rj = r % 10;
                if (ri >= 1 && ri <= 8 && rj >= 1 && rj <= 8) {
                    float p = acc[j][jj];
                    float v = p * p * invr[j] * invc[jj];
                    int flat = l * 64 + (ri - 1) * 8 + (rj - 1);
                    s_sm[flat] = v;
                    if (v > bestv) { bestv = v; besti = flat; }  // ascending order
                }
            }
        }
    }
    // wave argmax (first-index ties), then 4-entry combine
    #pragma unroll
    for (int d = 1; d < 64; d <<= 1) {
        float ov = __shfl_xor(bestv, d);
        int   oi = __shfl_xor(besti, d);
        if (ov > bestv || (ov == bestv && oi < besti)) { bestv = ov; besti = oi; }
    }
    if ((t & 63) == 0) { s_wval[w] = bestv; s_widx[w] = besti; }
    __syncthreads();

    float bv = s_wval[0]; int best = s_widx[0];
    #pragma unroll
    for (int i = 1; i < 4; i++) {
        float v2 = s_wval[i]; int i2 = s_widx[i];
        if (v2 > bv || (v2 == bv && i2 < best)) { bv = v2; best = i2; }
    }
    const int idx_l = best >> 6;
    const int idx_r = best & 63;
    const int iids  = idx_r >> 3, jids = idx_r & 7;

    // ---- sm -> global (float4) ----
    float* o_sm = out + (size_t)13 * M + (size_t)m * 4096;
    for (int i = t; i < 1024; i += TPB)
        ((float4*)o_sm)[i] = ((const float4*)s_sm)[i];

    // ---- 3x3 conf_ff window (9 dots of length 8) ----
    if (t < 9) {
        int da = t / 3 - 1, db = t % 3 - 1;
        int wi = iids + da; if (wi < 0) wi += 10;
        int wj = jids + db; if (wj < 0) wj += 10;
        int rp = wi * 10 + wj;
        float dot = 0.0f;
        #pragma unroll
        for (int c = 0; c < 8; c++)
            dot += s_ff0[idx_l * 8 + c] * s_f1[rp * F1S + 56 + c];
        s_win[t] = dot * 0.35355339059327373f;       // 1/sqrt(8)
    }
    __syncthreads();

    if (t == 0) {
        float ww[9], mx = -INFINITY;
        #pragma unroll
        for (int i = 0; i < 9; i++) { ww[i] = s_win[i] * 0.1f; mx = fmaxf(mx, ww[i]); }
        float sum = 0.0f;
        #pragma unroll
        for (int i = 0; i < 9; i++) { ww[i] = __expf(ww[i] - mx); sum += ww[i]; }
        float inv = 1.0f / sum;
        float* o_probs = out + (size_t)4 * M + (size_t)m * 9;
        float cx = 0.0f, cy = 0.0f;
        #pragma unroll
        for (int i = 0; i < 9; i++) {
            float p = ww[i] * inv;
            o_probs[i] = p;
            cx += p * (float)(i % 3 - 1);
            cy += p * (float)(i / 3 - 1);
        }
        float dlx = (float)(idx_l & 7) - 3.5f;
        float dly = (float)(idx_l >> 3) - 3.5f;
        out[2 * m]     = mk0[2 * m]     + dlx * scale;
        out[2 * m + 1] = mk0[2 * m + 1] + dly * scale;
        float drx = (float)jids - 3.5f;
        float dry = (float)iids - 3.5f;
        float* o1 = out + (size_t)2 * M;
        o1[2 * m]     = mk1[2 * m]     + (drx + cx) * scale;
        o1[2 * m + 1] = mk1[2 * m + 1] + (dry + cy) * scale;
    }
}

extern "C" void kernel_launch(void* const* d_in, const int* in_sizes, int n_in,
                              void* d_out, int out_size, void* d_ws, size_t ws_size,
                              hipStream_t stream) {
    const float* feat0 = (const float*)d_in[0];
    const float* feat1 = (const float*)d_in[1];
    const float* mk0   = (const float*)d_in[2];
    const float* mk1   = (const float*)d_in[3];
    const int*   hw0_i = (const int*)d_in[6];
    const int*   hw0_f = (const int*)d_in[7];
    const int M = in_sizes[0] / 4096;

    fine_matching_kernel<<<M, TPB, 0, stream>>>(
        feat0, feat1, mk0, mk1, hw0_i, hw0_f, (float*)d_out, M);
}

// Round 3
// 457.966 us; speedup vs baseline: 1.3105x; 1.0594x over previous
//
#include <hip/hip_runtime.h>
#include <math.h>
#include <limits.h>

// FineMatching: one block per m (M=8192), 256 threads, 3 blocks/CU.
// GEMM on matrix cores via fp16 hi/lo split (3-term MFMA, ~2^-22 accurate).
// d_out (fp32 concat): mkpts0_f[M][2] | mkpts1_f[M][2] | probs[M][9] | sm[M][64][64]

constexpr int TPB = 256;

typedef _Float16 half8_t __attribute__((ext_vector_type(8)));
typedef _Float16 half4_t __attribute__((ext_vector_type(4)));
typedef float    float4_t __attribute__((ext_vector_type(4)));

struct __align__(16) SMem {
    union {
        struct {
            unsigned short f1h[100 * 56];   // 11200 B, 16B-aligned rows (112 B stride)
            unsigned short f1l[100 * 56];   // at +11200 (16B-aligned)
        };
        float sm[64 * 64];                  // 16384 B overlay, valid after GEMM
    };
    unsigned short f0h[64 * 56];            // at +22400 (16B-aligned)
    unsigned short f0l[64 * 56];            // at +29568
    float ff0[64 * 8];                      // last-8 channels, exact fp32
    float ff1[100 * 8];
    float cpart[4][112];
    float csum[112];
    float wval[4];
    int   widx[4];
    float win[9];
};                                          // ~44.3 KB -> 3 blocks/CU

__global__ __launch_bounds__(TPB, 3) void fine_matching_kernel(
    const float* __restrict__ feat0,   // [M][64][64]
    const float* __restrict__ feat1,   // [M][100][64]
    const float* __restrict__ mk0,
    const float* __restrict__ mk1,
    const int* __restrict__ hw0_i,
    const int* __restrict__ hw0_f,
    float* __restrict__ out, int M)
{
    __shared__ SMem S;

    const int m = blockIdx.x;
    const int t = threadIdx.x;
    const int lane = t & 63;
    const int w = t >> 6;        // wave = l-tile (16 rows of l)
    const int col = lane & 15;   // MFMA n-index (r within tile) / A m-index
    const int q = lane >> 4;     // MFMA quad
    const float scale = (float)hw0_i[0] / (float)hw0_f[0];   // 2.0

    const float* g0 = feat0 + (size_t)m * 4096;
    const float* g1 = feat1 + (size_t)m * 6400;
    _Float16* f0h = (_Float16*)S.f0h;
    _Float16* f0l = (_Float16*)S.f0l;
    _Float16* f1h = (_Float16*)S.f1h;
    _Float16* f1l = (_Float16*)S.f1l;

    // ---- stage: global -> hi/lo f16 split (k<56) + exact fp32 ff tails ----
    for (int i = t; i < 1024; i += TPB) {            // feat0
        float4_t v = ((const float4_t*)g0)[i];
        int fl = i << 2, l = fl >> 6, c = fl & 63;
        if (c < 56) {
            half4_t hi, lo;
            #pragma unroll
            for (int j = 0; j < 4; j++) {
                float x = v[j];
                _Float16 h = (_Float16)x;
                hi[j] = h;
                lo[j] = (_Float16)(x - (float)h);
            }
            *(half4_t*)(f0h + l * 56 + c) = hi;
            *(half4_t*)(f0l + l * 56 + c) = lo;
        } else {
            *(float4_t*)&S.ff0[l * 8 + (c - 56)] = v;
        }
    }
    for (int i = t; i < 1600; i += TPB) {            // feat1
        float4_t v = ((const float4_t*)g1)[i];
        int fl = i << 2, l = fl >> 6, c = fl & 63;
        if (c < 56) {
            half4_t hi, lo;
            #pragma unroll
            for (int j = 0; j < 4; j++) {
                float x = v[j];
                _Float16 h = (_Float16)x;
                hi[j] = h;
                lo[j] = (_Float16)(x - (float)h);
            }
            *(half4_t*)(f1h + l * 56 + c) = hi;
            *(half4_t*)(f1l + l * 56 + c) = lo;
        } else {
            *(float4_t*)&S.ff1[l * 8 + (c - 56)] = v;
        }
    }
    __syncthreads();

    // ---- GEMM on MFMA: conf[64][112] = f0[:,:56] @ f1[:,:56]^T / 64 ----
    // wave w owns l in [16w,16w+16); 7 r-tiles of 16. K padded 56->64 by
    // zeroing the A-frag for quad 3 / kstep 1 (so B garbage there is harmless).
    float4_t acc[7];
    #pragma unroll
    for (int rt = 0; rt < 7; rt++)
        #pragma unroll
        for (int j = 0; j < 4; j++) acc[rt][j] = 0.0f;

    half8_t hz;
    #pragma unroll
    for (int j = 0; j < 8; j++) hz[j] = (_Float16)0.0f;

    const int arow = (16 * w + col) * 56;
    #pragma unroll
    for (int ks = 0; ks < 2; ks++) {
        int koff = ks ? (32 + q * 8) : (q * 8);
        const bool kz = (ks == 1) && (q == 3);       // k=56..63: pad region
        if (kz) koff = 0;                            // safe aligned addr, frag zeroed
        half8_t ah = *(const half8_t*)(f0h + arow + koff);
        half8_t al = *(const half8_t*)(f0l + arow + koff);
        if (kz) { ah = hz; al = hz; }
        #pragma unroll
        for (int rt = 0; rt < 7; rt++) {
            int brow = rt * 16 + col;
            if (brow > 99) brow = 99;                // clamp: garbage masked later
            const int bo = brow * 56 + koff;
            half8_t bh = *(const half8_t*)(f1h + bo);
            half8_t bl = *(const half8_t*)(f1l + bo);
            acc[rt] = __builtin_amdgcn_mfma_f32_16x16x32_f16(ah, bh, acc[rt], 0, 0, 0);
            acc[rt] = __builtin_amdgcn_mfma_f32_16x16x32_f16(al, bh, acc[rt], 0, 0, 0);
            acc[rt] = __builtin_amdgcn_mfma_f32_16x16x32_f16(ah, bl, acc[rt], 0, 0, 0);
        }
    }

    // C layout: lane holds C[l = 16w + 4q + j][r = 16rt + col], j = 0..3
    // p = exp(conf); no max-subtract (conf O(1), softmax shift-invariant)
    float p[7][4];
    #pragma unroll
    for (int rt = 0; rt < 7; rt++) {
        const bool rvalid = (rt < 6) || (col < 4);   // r < 100
        #pragma unroll
        for (int j = 0; j < 4; j++) {
            float c = acc[rt][j] * (1.0f / 64.0f);
            p[rt][j] = rvalid ? __expf(c) : 0.0f;
        }
    }

    // row sums (over r, per l): lanes sharing l differ only in low-4 bits
    float invr[4];
    #pragma unroll
    for (int j = 0; j < 4; j++) {
        float s = 0.0f;
        #pragma unroll
        for (int rt = 0; rt < 7; rt++) s += p[rt][j];
        s += __shfl_xor(s, 1); s += __shfl_xor(s, 2);
        s += __shfl_xor(s, 4); s += __shfl_xor(s, 8);
        invr[j] = 1.0f / s;
    }

    // col sums (over l, per r): in-thread over j, xor over quads, LDS over waves
    #pragma unroll
    for (int rt = 0; rt < 7; rt++) {
        float s = p[rt][0] + p[rt][1] + p[rt][2] + p[rt][3];
        s += __shfl_xor(s, 16);
        s += __shfl_xor(s, 32);
        if (lane < 16) S.cpart[w][rt * 16 + col] = s;
    }
    __syncthreads();
    if (t < 112)
        S.csum[t] = S.cpart[0][t] + S.cpart[1][t] + S.cpart[2][t] + S.cpart[3][t];
    __syncthreads();    // also: all waves past GEMM -> safe to overlay S.sm on f1

    float invc[7];
    #pragma unroll
    for (int rt = 0; rt < 7; rt++) {
        const bool rvalid = (rt < 6) || (col < 4);
        invc[rt] = rvalid ? 1.0f / S.csum[rt * 16 + col] : 0.0f;
    }

    // ---- sm = p^2/(rsum*csum), crop 10x10 -> 8x8, argmax ----
    float* s_sm = S.sm;
    float bestv = -INFINITY; int besti = INT_MAX;
    #pragma unroll
    for (int j = 0; j < 4; j++) {
        const int l = 16 * w + 4 * q + j;
        #pragma unroll
        for (int rt = 0; rt < 7; rt++) {
            const int r = rt * 16 + col;
            if (r < 100) {
                const int ri = r / 10, rj = r - ri * 10;
                if (ri >= 1 && ri <= 8 && rj >= 1 && rj <= 8) {
                    float pv = p[rt][j];
                    float v = pv * pv * invr[j] * invc[rt];
                    int flat = l * 64 + (ri - 1) * 8 + (rj - 1);
                    s_sm[flat] = v;
                    if (v > bestv) { bestv = v; besti = flat; }  // ascending flat
                }
            }
        }
    }
    #pragma unroll
    for (int d = 1; d < 64; d <<= 1) {               // wave argmax, first-index ties
        float ov = __shfl_xor(bestv, d);
        int   oi = __shfl_xor(besti, d);
        if (ov > bestv || (ov == bestv && oi < besti)) { bestv = ov; besti = oi; }
    }
    if (lane == 0) { S.wval[w] = bestv; S.widx[w] = besti; }
    __syncthreads();

    float bv = S.wval[0]; int best = S.widx[0];
    #pragma unroll
    for (int i = 1; i < 4; i++) {
        float v2 = S.wval[i]; int i2 = S.widx[i];
        if (v2 > bv || (v2 == bv && i2 < best)) { bv = v2; best = i2; }
    }
    const int idx_l = best >> 6;
    const int idx_r = best & 63;
    const int iids  = idx_r >> 3, jids = idx_r & 7;

    // ---- sm -> global (float4) ----
    float* o_sm = out + (size_t)13 * M + (size_t)m * 4096;
    for (int i = t; i < 1024; i += TPB)
        ((float4_t*)o_sm)[i] = ((const float4_t*)s_sm)[i];

    // ---- 3x3 conf_ff window (exact fp32: 9 dots of length 8) ----
    if (t < 9) {
        int da = t / 3 - 1, db = t % 3 - 1;
        int wi = iids + da; if (wi < 0) wi += 10;
        int wj = jids + db; if (wj < 0) wj += 10;
        int rp = wi * 10 + wj;
        float dot = 0.0f;
        #pragma unroll
        for (int c = 0; c < 8; c++)
            dot += S.ff0[idx_l * 8 + c] * S.ff1[rp * 8 + c];
        S.win[t] = dot * 0.35355339059327373f;       // 1/sqrt(8)
    }
    __syncthreads();

    if (t == 0) {
        float ww[9], mx = -INFINITY;
        #pragma unroll
        for (int i = 0; i < 9; i++) { ww[i] = S.win[i] * 0.1f; mx = fmaxf(mx, ww[i]); }
        float sum = 0.0f;
        #pragma unroll
        for (int i = 0; i < 9; i++) { ww[i] = __expf(ww[i] - mx); sum += ww[i]; }
        float inv = 1.0f / sum;
        float* o_probs = out + (size_t)4 * M + (size_t)m * 9;
        float cx = 0.0f, cy = 0.0f;
        #pragma unroll
        for (int i = 0; i < 9; i++) {
            float pb = ww[i] * inv;
            o_probs[i] = pb;
            cx += pb * (float)(i % 3 - 1);
            cy += pb * (float)(i / 3 - 1);
        }
        float dlx = (float)(idx_l & 7) - 3.5f;
        float dly = (float)(idx_l >> 3) - 3.5f;
        out[2 * m]     = mk0[2 * m]     + dlx * scale;
        out[2 * m + 1] = mk0[2 * m + 1] + dly * scale;
        float drx = (float)jids - 3.5f;
        float dry = (float)iids - 3.5f;
        float* o1 = out + (size_t)2 * M;
        o1[2 * m]     = mk1[2 * m]     + (drx + cx) * scale;
        o1[2 * m + 1] = mk1[2 * m + 1] + (dry + cy) * scale;
    }
}

extern "C" void kernel_launch(void* const* d_in, const int* in_sizes, int n_in,
                              void* d_out, int out_size, void* d_ws, size_t ws_size,
                              hipStream_t stream) {
    const float* feat0 = (const float*)d_in[0];
    const float* feat1 = (const float*)d_in[1];
    const float* mk0   = (const float*)d_in[2];
    const float* mk1   = (const float*)d_in[3];
    const int*   hw0_i = (const int*)d_in[6];
    const int*   hw0_f = (const int*)d_in[7];
    const int M = in_sizes[0] / 4096;

    fine_matching_kernel<<<M, TPB, 0, stream>>>(
        feat0, feat1, mk0, mk1, hw0_i, hw0_f, (float*)d_out, M);
}